// Round 6
// baseline (440.141 us; speedup 1.0000x reference)
//
#include <hip/hip_runtime.h>

#define N_NODES 50000
#define N_EDGES 800000

typedef __bf16 v8bf __attribute__((ext_vector_type(8)));
typedef float  v4f  __attribute__((ext_vector_type(4)));

__device__ __forceinline__ float bf2f(ushort u) {
    return __uint_as_float(((unsigned int)u) << 16);
}
__device__ __forceinline__ ushort f2bf(float f) {
    unsigned int u = __float_as_uint(f);
    u += 0x7FFFu + ((u >> 16) & 1u);   // RNE
    return (ushort)(u >> 16);
}

// ---------------- K1: fused w-prep (blocks 0..255) + row histogram (rest) -----
// wprep: block b transposes W column b -> WT row b, with local dtype detection
// on the contiguous ushort chunk W[b*256 .. +255] (bf16 glorot: |w|<=0.153 -> 0
// hits; f32-as-ushort: ~half are uniform mantissa halves -> ~64 hits).
__global__ void k_prep(const void* __restrict__ Wv, ushort* __restrict__ WT,
                       int* __restrict__ flag, const int* __restrict__ rows,
                       int* __restrict__ counts) {
    if (blockIdx.x < 256) {
        __shared__ int s_cnt;
        const int n = blockIdx.x;
        const int k = threadIdx.x;
        if (k == 0) s_cnt = 0;
        __syncthreads();
        const ushort* Wu = (const ushort*)Wv;
        float dv = bf2f(Wu[n * 256 + k]);
        unsigned long long m = __ballot(fabsf(dv) > 0.2f);
        if ((k & 63) == 0 && m) atomicAdd(&s_cnt, __popcll(m));
        __syncthreads();
        bool isf32 = (s_cnt > 8);
        if (k == 0 && s_cnt > 0) atomicAdd(flag, s_cnt);
        ushort v;
        if (isf32) v = f2bf(((const float*)Wv)[k * 256 + n]);
        else       v = Wu[k * 256 + n];
        WT[n * 256 + k] = v;
    } else {
        int e = (blockIdx.x - 256) * 256 + threadIdx.x;
        if (e < N_EDGES) atomicAdd(&counts[rows[e]], 1);
    }
}

// ---------------- K2: single-block exclusive scan (1024 thr), inits cursor ----
__global__ __launch_bounds__(1024) void k_scan(const int* __restrict__ counts,
                                               int* __restrict__ rptr,
                                               int* __restrict__ cursor) {
    const int t = threadIdx.x;
    const int CH = 49;                      // 1024*49 = 50176 >= 50000
    const int base = t * CH;
    const int end  = min(base + CH, N_NODES);
    int s = 0;
    for (int i = base; i < end; ++i) s += counts[i];

    const int lane = t & 63, w = t >> 6;
    __shared__ int wsum[16];
    int ps = s;
    #pragma unroll
    for (int d = 1; d < 64; d <<= 1) {
        int v = __shfl_up(ps, d, 64);
        if (lane >= d) ps += v;
    }
    if (lane == 63) wsum[w] = ps;
    __syncthreads();
    if (w == 0) {
        int v = (lane < 16) ? wsum[lane] : 0;
        #pragma unroll
        for (int d = 1; d < 16; d <<= 1) {
            int u = __shfl_up(v, d, 64);
            if (lane >= d) v += u;
        }
        if (lane < 16) wsum[lane] = v;
    }
    __syncthreads();
    int run = (ps - s) + (w > 0 ? wsum[w - 1] : 0);   // thread-exclusive prefix
    for (int i = base; i < end; ++i) {
        int c = counts[i];
        rptr[i] = run;
        cursor[i] = run;
        run += c;
    }
}

// ---------------- K3: scatter edges into CSR order, packed (col<<16|bf16) -----
__global__ void k_scatter(const int* __restrict__ rows, const int* __restrict__ cols,
                          const void* __restrict__ valsv, int* __restrict__ cursor,
                          unsigned int* __restrict__ ev, const int* __restrict__ flag) {
    bool isf32 = (*flag > 1000);
    int e = blockIdx.x * 256 + threadIdx.x;
    if (e < N_EDGES) {
        int r = rows[e];
        int p = atomicAdd(&cursor[r], 1);
        ushort v;
        if (isf32) v = f2bf(((const float*)valsv)[e]);
        else       v = ((const ushort*)valsv)[e];
        ev[p] = ((unsigned int)cols[e] << 16) | (unsigned int)v;
    }
}

// ---------------- K4: SpMM  T = Adj * X   (T -> d_out, pre-projection) --------
// One wave per row (full 512 B row gather -> best fill-path efficiency).
// ev for the row loaded once per 64-edge chunk (coalesced) + __shfl broadcast;
// unroll-4 inner loop -> 4 independent X row-loads in flight per wave.
__global__ __launch_bounds__(256) void k_spmm(const void* __restrict__ Xv,
                                              const unsigned int* __restrict__ ev,
                                              const int* __restrict__ rptr,
                                              const int* __restrict__ counts,
                                              const int* __restrict__ flag,
                                              void* __restrict__ T) {
    bool isf32 = (*flag > 1000);
    const int wv   = threadIdx.x >> 6;
    const int lane = threadIdx.x & 63;
    const int r = blockIdx.x * 4 + wv;          // 12500*4 = 50000 exactly
    const int start = rptr[r];
    const int cnt   = counts[r];

    float a0 = 0.f, a1 = 0.f, a2 = 0.f, a3 = 0.f;

    if (isf32) {
        const float* xp = (const float*)Xv + lane * 4;
        for (int base = 0; base < cnt; base += 64) {
            int idx = base + lane;
            unsigned int chunk = (idx < cnt) ? ev[start + idx] : 0u;
            int m = min(64, cnt - base);
            int j = 0;
            for (; j + 4 <= m; j += 4) {
                unsigned int e0 = __shfl(chunk, j,     64);
                unsigned int e1 = __shfl(chunk, j + 1, 64);
                unsigned int e2 = __shfl(chunk, j + 2, 64);
                unsigned int e3 = __shfl(chunk, j + 3, 64);
                v4f x0 = *(const v4f*)(xp + (e0 >> 16) * 256);
                v4f x1 = *(const v4f*)(xp + (e1 >> 16) * 256);
                v4f x2 = *(const v4f*)(xp + (e2 >> 16) * 256);
                v4f x3 = *(const v4f*)(xp + (e3 >> 16) * 256);
                float v0 = __uint_as_float(e0 << 16);
                float v1 = __uint_as_float(e1 << 16);
                float v2 = __uint_as_float(e2 << 16);
                float v3 = __uint_as_float(e3 << 16);
                a0 = fmaf(v0, x0.x, a0); a1 = fmaf(v0, x0.y, a1);
                a2 = fmaf(v0, x0.z, a2); a3 = fmaf(v0, x0.w, a3);
                a0 = fmaf(v1, x1.x, a0); a1 = fmaf(v1, x1.y, a1);
                a2 = fmaf(v1, x1.z, a2); a3 = fmaf(v1, x1.w, a3);
                a0 = fmaf(v2, x2.x, a0); a1 = fmaf(v2, x2.y, a1);
                a2 = fmaf(v2, x2.z, a2); a3 = fmaf(v2, x2.w, a3);
                a0 = fmaf(v3, x3.x, a0); a1 = fmaf(v3, x3.y, a1);
                a2 = fmaf(v3, x3.z, a2); a3 = fmaf(v3, x3.w, a3);
            }
            for (; j < m; ++j) {
                unsigned int e0 = __shfl(chunk, j, 64);
                v4f x0 = *(const v4f*)(xp + (e0 >> 16) * 256);
                float v0 = __uint_as_float(e0 << 16);
                a0 = fmaf(v0, x0.x, a0); a1 = fmaf(v0, x0.y, a1);
                a2 = fmaf(v0, x0.z, a2); a3 = fmaf(v0, x0.w, a3);
            }
        }
        v4f o = { a0, a1, a2, a3 };
        __builtin_nontemporal_store(o, (v4f*)((float*)T + (size_t)r * 256 + lane * 4));
    } else {
        const ushort* xp = (const ushort*)Xv + lane * 4;
        for (int base = 0; base < cnt; base += 64) {
            int idx = base + lane;
            unsigned int chunk = (idx < cnt) ? ev[start + idx] : 0u;
            int m = min(64, cnt - base);
            int j = 0;
            for (; j + 4 <= m; j += 4) {
                unsigned int e0 = __shfl(chunk, j,     64);
                unsigned int e1 = __shfl(chunk, j + 1, 64);
                unsigned int e2 = __shfl(chunk, j + 2, 64);
                unsigned int e3 = __shfl(chunk, j + 3, 64);
                ushort4 x0 = *(const ushort4*)(xp + (e0 >> 16) * 256);
                ushort4 x1 = *(const ushort4*)(xp + (e1 >> 16) * 256);
                ushort4 x2 = *(const ushort4*)(xp + (e2 >> 16) * 256);
                ushort4 x3 = *(const ushort4*)(xp + (e3 >> 16) * 256);
                float v0 = __uint_as_float(e0 << 16);
                float v1 = __uint_as_float(e1 << 16);
                float v2 = __uint_as_float(e2 << 16);
                float v3 = __uint_as_float(e3 << 16);
                a0 = fmaf(v0, bf2f(x0.x), a0); a1 = fmaf(v0, bf2f(x0.y), a1);
                a2 = fmaf(v0, bf2f(x0.z), a2); a3 = fmaf(v0, bf2f(x0.w), a3);
                a0 = fmaf(v1, bf2f(x1.x), a0); a1 = fmaf(v1, bf2f(x1.y), a1);
                a2 = fmaf(v1, bf2f(x1.z), a2); a3 = fmaf(v1, bf2f(x1.w), a3);
                a0 = fmaf(v2, bf2f(x2.x), a0); a1 = fmaf(v2, bf2f(x2.y), a1);
                a2 = fmaf(v2, bf2f(x2.z), a2); a3 = fmaf(v2, bf2f(x2.w), a3);
                a0 = fmaf(v3, bf2f(x3.x), a0); a1 = fmaf(v3, bf2f(x3.y), a1);
                a2 = fmaf(v3, bf2f(x3.z), a2); a3 = fmaf(v3, bf2f(x3.w), a3);
            }
            for (; j < m; ++j) {
                unsigned int e0 = __shfl(chunk, j, 64);
                ushort4 x0 = *(const ushort4*)(xp + (e0 >> 16) * 256);
                float v0 = __uint_as_float(e0 << 16);
                a0 = fmaf(v0, bf2f(x0.x), a0); a1 = fmaf(v0, bf2f(x0.y), a1);
                a2 = fmaf(v0, bf2f(x0.z), a2); a3 = fmaf(v0, bf2f(x0.w), a3);
            }
        }
        unsigned long long p =
            (unsigned long long)f2bf(a0)
          | ((unsigned long long)f2bf(a1) << 16)
          | ((unsigned long long)f2bf(a2) << 32)
          | ((unsigned long long)f2bf(a3) << 48);
        __builtin_nontemporal_store(p,
            (unsigned long long*)((ushort*)T + (size_t)r * 256 + lane * 4));
    }
}

// ---------------- K5: in-place GEMM  out = relu(T * W), T lives in d_out ------
// A (64x256) staged in LDS once (single barrier), A-frags hoisted to registers,
// B-frags loaded directly from global WT (131 KB, L2-hot).
#define ASTRIDE 264
__global__ __launch_bounds__(256) void k_gemm(void* __restrict__ Tv,
                                              const ushort* __restrict__ WT,
                                              const int* __restrict__ flag) {
    bool isf32 = (*flag > 1000);
    __shared__ __align__(16) ushort sA[64 * ASTRIDE];
    const int t = threadIdx.x;
    const int mBase = blockIdx.x * 64;

    {
        int m = t >> 2, g = t & 3;
        int row = mBase + m;
        bool ok = row < N_NODES;
        if (isf32) {
            const float* src = (const float*)Tv + (size_t)row * 256;
            #pragma unroll
            for (int it = 0; it < 8; ++it) {
                int kk = (g + it * 4) * 8;
                float4 lo = ok ? *(const float4*)(src + kk)     : make_float4(0.f, 0.f, 0.f, 0.f);
                float4 hi = ok ? *(const float4*)(src + kk + 4) : make_float4(0.f, 0.f, 0.f, 0.f);
                uint4 val;
                val.x = (uint)f2bf(lo.x) | ((uint)f2bf(lo.y) << 16);
                val.y = (uint)f2bf(lo.z) | ((uint)f2bf(lo.w) << 16);
                val.z = (uint)f2bf(hi.x) | ((uint)f2bf(hi.y) << 16);
                val.w = (uint)f2bf(hi.z) | ((uint)f2bf(hi.w) << 16);
                *(uint4*)&sA[m * ASTRIDE + kk] = val;
            }
        } else {
            const ushort* src = (const ushort*)Tv + (size_t)row * 256;
            #pragma unroll
            for (int it = 0; it < 8; ++it) {
                int kk = (g + it * 4) * 8;
                uint4 val = ok ? *(const uint4*)(src + kk) : make_uint4(0u, 0u, 0u, 0u);
                *(uint4*)&sA[m * ASTRIDE + kk] = val;
            }
        }
    }
    __syncthreads();

    const int lane = t & 63, wv = t >> 6;
    const int wm = (wv & 1) * 32, wn = (wv >> 1) * 32;
    const int fr = lane & 15;
    const int q  = lane >> 4;

    v8bf A0[8], A1[8];
    #pragma unroll
    for (int ks = 0; ks < 8; ++ks) {
        A0[ks] = *(const v8bf*)&sA[(wm +      fr) * ASTRIDE + ks * 32 + q * 8];
        A1[ks] = *(const v8bf*)&sA[(wm + 16 + fr) * ASTRIDE + ks * 32 + q * 8];
    }

    for (int nb = 0; nb < 4; ++nb) {
        const int nBase = nb * 64;
        v4f acc[2][2] = {};
        const ushort* b0p = WT + (size_t)(nBase + wn +      fr) * 256 + q * 8;
        const ushort* b1p = WT + (size_t)(nBase + wn + 16 + fr) * 256 + q * 8;

        #pragma unroll
        for (int ks = 0; ks < 8; ++ks) {
            v8bf b0 = *(const v8bf*)(b0p + ks * 32);
            v8bf b1 = *(const v8bf*)(b1p + ks * 32);
            acc[0][0] = __builtin_amdgcn_mfma_f32_16x16x32_bf16(A0[ks], b0, acc[0][0], 0, 0, 0);
            acc[0][1] = __builtin_amdgcn_mfma_f32_16x16x32_bf16(A0[ks], b1, acc[0][1], 0, 0, 0);
            acc[1][0] = __builtin_amdgcn_mfma_f32_16x16x32_bf16(A1[ks], b0, acc[1][0], 0, 0, 0);
            acc[1][1] = __builtin_amdgcn_mfma_f32_16x16x32_bf16(A1[ks], b1, acc[1][1], 0, 0, 0);
        }

        #pragma unroll
        for (int tm = 0; tm < 2; tm++) {
            #pragma unroll
            for (int tn = 0; tn < 2; tn++) {
                #pragma unroll
                for (int rr = 0; rr < 4; rr++) {
                    int grow = mBase + wm + tm * 16 + q * 4 + rr;
                    if (grow < N_NODES) {
                        int gcol = nBase + wn + tn * 16 + fr;
                        float v = fmaxf(acc[tm][tn][rr], 0.f);
                        if (isf32) ((float*)Tv)[(size_t)grow * 256 + gcol] = v;
                        else       ((ushort*)Tv)[(size_t)grow * 256 + gcol] = f2bf(v);
                    }
                }
            }
        }
    }
}

// ---------------- workspace layout (bytes) — total ~3.93 MB ----------------
#define OFF_FLAG   ((size_t)0)          //       256
#define OFF_COUNTS ((size_t)256)        //   200,000
#define OFF_RPTR   ((size_t)200256)     //   200,000
#define OFF_CURSOR ((size_t)400256)     //   200,000
#define OFF_WT     ((size_t)600256)     //   131,072
#define OFF_EV     ((size_t)731328)     // 3,200,000 packed uint32 edges
// end = 3,931,328

extern "C" void kernel_launch(void* const* d_in, const int* in_sizes, int n_in,
                              void* d_out, int out_size, void* d_ws, size_t ws_size,
                              hipStream_t stream) {
    const void* X    = d_in[0];
    const void* W    = d_in[1];
    const void* VALS = d_in[2];
    const int*  ROWS = (const int*)d_in[3];
    const int*  COLS = (const int*)d_in[4];

    char* ws = (char*)d_ws;
    int*          flag   = (int*)(ws + OFF_FLAG);
    int*          counts = (int*)(ws + OFF_COUNTS);
    int*          rptr   = (int*)(ws + OFF_RPTR);
    int*          cursor = (int*)(ws + OFF_CURSOR);
    ushort*       WT     = (ushort*)(ws + OFF_WT);
    unsigned int* ev     = (unsigned int*)(ws + OFF_EV);

    (void)hipMemsetAsync(ws, 0, 200256, stream);   // flag + counts only

    k_prep<<<256 + (N_EDGES + 255) / 256, 256, 0, stream>>>(W, WT, flag, ROWS, counts);
    k_scan<<<1, 1024, 0, stream>>>(counts, rptr, cursor);
    k_scatter<<<(N_EDGES + 255) / 256, 256, 0, stream>>>(ROWS, COLS, VALS, cursor, ev, flag);
    k_spmm<<<N_NODES / 4, 256, 0, stream>>>(X, ev, rptr, counts, flag, d_out);
    k_gemm<<<(N_NODES + 63) / 64, 256, 0, stream>>>(d_out, WT, flag);
}

// Round 7
// 343.824 us; speedup vs baseline: 1.2801x; 1.2801x over previous
//
#include <hip/hip_runtime.h>

#define N_NODES 50000
#define N_EDGES 800000

typedef __bf16 v8bf __attribute__((ext_vector_type(8)));
typedef float  v4f  __attribute__((ext_vector_type(4)));

__device__ __forceinline__ float bf2f(ushort u) {
    return __uint_as_float(((unsigned int)u) << 16);
}
__device__ __forceinline__ ushort f2bf(float f) {
    unsigned int u = __float_as_uint(f);
    u += 0x7FFFu + ((u >> 16) & 1u);   // RNE
    return (ushort)(u >> 16);
}

// ---------------- w prep: local dtype detect + transpose + global flag ----------
__global__ void k_wprep(const void* __restrict__ Wv, ushort* __restrict__ WT,
                        int* __restrict__ flag) {
    __shared__ int s_cnt;
    const int n = blockIdx.x;
    const int k = threadIdx.x;
    if (k == 0) s_cnt = 0;
    __syncthreads();
    const ushort* Wu = (const ushort*)Wv;
    float dv = bf2f(Wu[n * 256 + k]);
    unsigned long long m = __ballot(fabsf(dv) > 0.2f);
    if ((k & 63) == 0 && m) atomicAdd(&s_cnt, __popcll(m));
    __syncthreads();
    bool isf32 = (s_cnt > 8);
    if (k == 0 && s_cnt > 0) atomicAdd(flag, s_cnt);
    ushort v;
    if (isf32) v = f2bf(((const float*)Wv)[k * 256 + n]);
    else       v = Wu[k * 256 + n];
    WT[n * 256 + k] = v;
}

// ---------------- histogram of rows ----------------
__global__ void k_hist(const int* __restrict__ rows, int* __restrict__ counts) {
    int e = blockIdx.x * 256 + threadIdx.x;
    if (e < N_EDGES) atomicAdd(&counts[rows[e]], 1);
}

// ---------------- distributed scan (3 kernels) ----------------
__global__ void k_scan1(const int* __restrict__ counts, int* __restrict__ incl,
                        int* __restrict__ bsums, int n) {
    int t = threadIdx.x;
    int i = blockIdx.x * 256 + t;
    int v = (i < n) ? counts[i] : 0;
    int lane = t & 63, wv = t >> 6;
    __shared__ int wsum[4];
    int s = v;
    #pragma unroll
    for (int d = 1; d < 64; d <<= 1) {
        int tt = __shfl_up(s, d, 64);
        if (lane >= d) s += tt;
    }
    if (lane == 63) wsum[wv] = s;
    __syncthreads();
    int add = 0;
    #pragma unroll
    for (int k = 0; k < 4; k++) if (k < wv) add += wsum[k];
    s += add;
    if (i < n) incl[i] = s;
    if (t == 255) bsums[blockIdx.x] = s;
}

__global__ void k_scan2(int* __restrict__ bsums, int nb) {
    int t = threadIdx.x;
    int v = (t < nb) ? bsums[t] : 0;
    int lane = t & 63, wv = t >> 6;
    __shared__ int wsum[4];
    int s = v;
    #pragma unroll
    for (int d = 1; d < 64; d <<= 1) {
        int tt = __shfl_up(s, d, 64);
        if (lane >= d) s += tt;
    }
    if (lane == 63) wsum[wv] = s;
    __syncthreads();
    int add = 0;
    #pragma unroll
    for (int k = 0; k < 4; k++) if (k < wv) add += wsum[k];
    s += add;
    if (t < nb) bsums[t] = s - v;
}

// incl -> excl, and initialize cursor = rptr (so scatter needs one atomic only)
__global__ void k_scan3(int* __restrict__ row_ptr, int* __restrict__ cursor,
                        const int* __restrict__ counts, const int* __restrict__ boff,
                        int n) {
    int i = blockIdx.x * 256 + threadIdx.x;
    if (i < n) {
        int v = row_ptr[i] + boff[blockIdx.x] - counts[i];
        row_ptr[i] = v;
        cursor[i]  = v;
    }
}

// ---------------- scatter edges into CSR order, packed (col<<16|bf16) -----
__global__ void k_scatter(const int* __restrict__ rows, const int* __restrict__ cols,
                          const void* __restrict__ valsv, int* __restrict__ cursor,
                          unsigned int* __restrict__ ev, const int* __restrict__ flag) {
    bool isf32 = (*flag > 1000);
    int e = blockIdx.x * 256 + threadIdx.x;
    if (e < N_EDGES) {
        int r = rows[e];
        int p = atomicAdd(&cursor[r], 1);
        ushort v;
        if (isf32) v = f2bf(((const float*)valsv)[e]);
        else       v = ((const ushort*)valsv)[e];
        ev[p] = ((unsigned int)cols[e] << 16) | (unsigned int)v;
    }
}

// ---------------- SpMM  T = Adj * X  (one wave/row, shfl-broadcast ev) --------
__global__ __launch_bounds__(256) void k_spmm(const void* __restrict__ Xv,
                                              const unsigned int* __restrict__ ev,
                                              const int* __restrict__ rptr,
                                              const int* __restrict__ counts,
                                              const int* __restrict__ flag,
                                              void* __restrict__ T) {
    bool isf32 = (*flag > 1000);
    const int wv   = threadIdx.x >> 6;
    const int lane = threadIdx.x & 63;
    const int r = blockIdx.x * 4 + wv;          // 12500*4 = 50000 exactly
    const int start = rptr[r];
    const int cnt   = counts[r];

    float a0 = 0.f, a1 = 0.f, a2 = 0.f, a3 = 0.f;

    if (isf32) {
        const float* xp = (const float*)Xv + lane * 4;
        for (int base = 0; base < cnt; base += 64) {
            int idx = base + lane;
            unsigned int chunk = (idx < cnt) ? ev[start + idx] : 0u;
            int m = min(64, cnt - base);
            int j = 0;
            for (; j + 4 <= m; j += 4) {
                unsigned int e0 = __shfl(chunk, j,     64);
                unsigned int e1 = __shfl(chunk, j + 1, 64);
                unsigned int e2 = __shfl(chunk, j + 2, 64);
                unsigned int e3 = __shfl(chunk, j + 3, 64);
                v4f x0 = *(const v4f*)(xp + (e0 >> 16) * 256);
                v4f x1 = *(const v4f*)(xp + (e1 >> 16) * 256);
                v4f x2 = *(const v4f*)(xp + (e2 >> 16) * 256);
                v4f x3 = *(const v4f*)(xp + (e3 >> 16) * 256);
                float v0 = __uint_as_float(e0 << 16);
                float v1 = __uint_as_float(e1 << 16);
                float v2 = __uint_as_float(e2 << 16);
                float v3 = __uint_as_float(e3 << 16);
                a0 = fmaf(v0, x0.x, a0); a1 = fmaf(v0, x0.y, a1);
                a2 = fmaf(v0, x0.z, a2); a3 = fmaf(v0, x0.w, a3);
                a0 = fmaf(v1, x1.x, a0); a1 = fmaf(v1, x1.y, a1);
                a2 = fmaf(v1, x1.z, a2); a3 = fmaf(v1, x1.w, a3);
                a0 = fmaf(v2, x2.x, a0); a1 = fmaf(v2, x2.y, a1);
                a2 = fmaf(v2, x2.z, a2); a3 = fmaf(v2, x2.w, a3);
                a0 = fmaf(v3, x3.x, a0); a1 = fmaf(v3, x3.y, a1);
                a2 = fmaf(v3, x3.z, a2); a3 = fmaf(v3, x3.w, a3);
            }
            for (; j < m; ++j) {
                unsigned int e0 = __shfl(chunk, j, 64);
                v4f x0 = *(const v4f*)(xp + (e0 >> 16) * 256);
                float v0 = __uint_as_float(e0 << 16);
                a0 = fmaf(v0, x0.x, a0); a1 = fmaf(v0, x0.y, a1);
                a2 = fmaf(v0, x0.z, a2); a3 = fmaf(v0, x0.w, a3);
            }
        }
        v4f o = { a0, a1, a2, a3 };
        __builtin_nontemporal_store(o, (v4f*)((float*)T + (size_t)r * 256 + lane * 4));
    } else {
        const ushort* xp = (const ushort*)Xv + lane * 4;
        for (int base = 0; base < cnt; base += 64) {
            int idx = base + lane;
            unsigned int chunk = (idx < cnt) ? ev[start + idx] : 0u;
            int m = min(64, cnt - base);
            int j = 0;
            for (; j + 4 <= m; j += 4) {
                unsigned int e0 = __shfl(chunk, j,     64);
                unsigned int e1 = __shfl(chunk, j + 1, 64);
                unsigned int e2 = __shfl(chunk, j + 2, 64);
                unsigned int e3 = __shfl(chunk, j + 3, 64);
                ushort4 x0 = *(const ushort4*)(xp + (e0 >> 16) * 256);
                ushort4 x1 = *(const ushort4*)(xp + (e1 >> 16) * 256);
                ushort4 x2 = *(const ushort4*)(xp + (e2 >> 16) * 256);
                ushort4 x3 = *(const ushort4*)(xp + (e3 >> 16) * 256);
                float v0 = __uint_as_float(e0 << 16);
                float v1 = __uint_as_float(e1 << 16);
                float v2 = __uint_as_float(e2 << 16);
                float v3 = __uint_as_float(e3 << 16);
                a0 = fmaf(v0, bf2f(x0.x), a0); a1 = fmaf(v0, bf2f(x0.y), a1);
                a2 = fmaf(v0, bf2f(x0.z), a2); a3 = fmaf(v0, bf2f(x0.w), a3);
                a0 = fmaf(v1, bf2f(x1.x), a0); a1 = fmaf(v1, bf2f(x1.y), a1);
                a2 = fmaf(v1, bf2f(x1.z), a2); a3 = fmaf(v1, bf2f(x1.w), a3);
                a0 = fmaf(v2, bf2f(x2.x), a0); a1 = fmaf(v2, bf2f(x2.y), a1);
                a2 = fmaf(v2, bf2f(x2.z), a2); a3 = fmaf(v2, bf2f(x2.w), a3);
                a0 = fmaf(v3, bf2f(x3.x), a0); a1 = fmaf(v3, bf2f(x3.y), a1);
                a2 = fmaf(v3, bf2f(x3.z), a2); a3 = fmaf(v3, bf2f(x3.w), a3);
            }
            for (; j < m; ++j) {
                unsigned int e0 = __shfl(chunk, j, 64);
                ushort4 x0 = *(const ushort4*)(xp + (e0 >> 16) * 256);
                float v0 = __uint_as_float(e0 << 16);
                a0 = fmaf(v0, bf2f(x0.x), a0); a1 = fmaf(v0, bf2f(x0.y), a1);
                a2 = fmaf(v0, bf2f(x0.z), a2); a3 = fmaf(v0, bf2f(x0.w), a3);
            }
        }
        unsigned long long p =
            (unsigned long long)f2bf(a0)
          | ((unsigned long long)f2bf(a1) << 16)
          | ((unsigned long long)f2bf(a2) << 32)
          | ((unsigned long long)f2bf(a3) << 48);
        __builtin_nontemporal_store(p,
            (unsigned long long*)((ushort*)T + (size_t)r * 256 + lane * 4));
    }
}

// ---------------- in-place GEMM  out = relu(T * W), T lives in d_out ------
#define ASTRIDE 264
__global__ __launch_bounds__(256) void k_gemm(void* __restrict__ Tv,
                                              const ushort* __restrict__ WT,
                                              const int* __restrict__ flag) {
    bool isf32 = (*flag > 1000);
    __shared__ __align__(16) ushort sA[64 * ASTRIDE];
    const int t = threadIdx.x;
    const int mBase = blockIdx.x * 64;

    {
        int m = t >> 2, g = t & 3;
        int row = mBase + m;
        bool ok = row < N_NODES;
        if (isf32) {
            const float* src = (const float*)Tv + (size_t)row * 256;
            #pragma unroll
            for (int it = 0; it < 8; ++it) {
                int kk = (g + it * 4) * 8;
                float4 lo = ok ? *(const float4*)(src + kk)     : make_float4(0.f, 0.f, 0.f, 0.f);
                float4 hi = ok ? *(const float4*)(src + kk + 4) : make_float4(0.f, 0.f, 0.f, 0.f);
                uint4 val;
                val.x = (uint)f2bf(lo.x) | ((uint)f2bf(lo.y) << 16);
                val.y = (uint)f2bf(lo.z) | ((uint)f2bf(lo.w) << 16);
                val.z = (uint)f2bf(hi.x) | ((uint)f2bf(hi.y) << 16);
                val.w = (uint)f2bf(hi.z) | ((uint)f2bf(hi.w) << 16);
                *(uint4*)&sA[m * ASTRIDE + kk] = val;
            }
        } else {
            const ushort* src = (const ushort*)Tv + (size_t)row * 256;
            #pragma unroll
            for (int it = 0; it < 8; ++it) {
                int kk = (g + it * 4) * 8;
                uint4 val = ok ? *(const uint4*)(src + kk) : make_uint4(0u, 0u, 0u, 0u);
                *(uint4*)&sA[m * ASTRIDE + kk] = val;
            }
        }
    }
    __syncthreads();

    const int lane = t & 63, wv = t >> 6;
    const int wm = (wv & 1) * 32, wn = (wv >> 1) * 32;
    const int fr = lane & 15;
    const int q  = lane >> 4;

    v8bf A0[8], A1[8];
    #pragma unroll
    for (int ks = 0; ks < 8; ++ks) {
        A0[ks] = *(const v8bf*)&sA[(wm +      fr) * ASTRIDE + ks * 32 + q * 8];
        A1[ks] = *(const v8bf*)&sA[(wm + 16 + fr) * ASTRIDE + ks * 32 + q * 8];
    }

    for (int nb = 0; nb < 4; ++nb) {
        const int nBase = nb * 64;
        v4f acc[2][2] = {};
        const ushort* b0p = WT + (size_t)(nBase + wn +      fr) * 256 + q * 8;
        const ushort* b1p = WT + (size_t)(nBase + wn + 16 + fr) * 256 + q * 8;

        #pragma unroll
        for (int ks = 0; ks < 8; ++ks) {
            v8bf b0 = *(const v8bf*)(b0p + ks * 32);
            v8bf b1 = *(const v8bf*)(b1p + ks * 32);
            acc[0][0] = __builtin_amdgcn_mfma_f32_16x16x32_bf16(A0[ks], b0, acc[0][0], 0, 0, 0);
            acc[0][1] = __builtin_amdgcn_mfma_f32_16x16x32_bf16(A0[ks], b1, acc[0][1], 0, 0, 0);
            acc[1][0] = __builtin_amdgcn_mfma_f32_16x16x32_bf16(A1[ks], b0, acc[1][0], 0, 0, 0);
            acc[1][1] = __builtin_amdgcn_mfma_f32_16x16x32_bf16(A1[ks], b1, acc[1][1], 0, 0, 0);
        }

        #pragma unroll
        for (int tm = 0; tm < 2; tm++) {
            #pragma unroll
            for (int tn = 0; tn < 2; tn++) {
                #pragma unroll
                for (int rr = 0; rr < 4; rr++) {
                    int grow = mBase + wm + tm * 16 + q * 4 + rr;
                    if (grow < N_NODES) {
                        int gcol = nBase + wn + tn * 16 + fr;
                        float v = fmaxf(acc[tm][tn][rr], 0.f);
                        if (isf32) ((float*)Tv)[(size_t)grow * 256 + gcol] = v;
                        else       ((ushort*)Tv)[(size_t)grow * 256 + gcol] = f2bf(v);
                    }
                }
            }
        }
    }
}

// ---------------- workspace layout (bytes) — total ~3.93 MB ----------------
#define OFF_FLAG   ((size_t)0)          //       256
#define OFF_COUNTS ((size_t)256)        //   200,000
#define OFF_RPTR   ((size_t)200256)     //   200,000
#define OFF_CURSOR ((size_t)400256)     //   200,000
#define OFF_BSUMS  ((size_t)600256)     //     1,024
#define OFF_WT     ((size_t)601280)     //   131,072
#define OFF_EV     ((size_t)732352)     // 3,200,000 packed uint32 edges

extern "C" void kernel_launch(void* const* d_in, const int* in_sizes, int n_in,
                              void* d_out, int out_size, void* d_ws, size_t ws_size,
                              hipStream_t stream) {
    const void* X    = d_in[0];
    const void* W    = d_in[1];
    const void* VALS = d_in[2];
    const int*  ROWS = (const int*)d_in[3];
    const int*  COLS = (const int*)d_in[4];

    char* ws = (char*)d_ws;
    int*          flag   = (int*)(ws + OFF_FLAG);
    int*          counts = (int*)(ws + OFF_COUNTS);
    int*          rptr   = (int*)(ws + OFF_RPTR);
    int*          cursor = (int*)(ws + OFF_CURSOR);
    int*          bsums  = (int*)(ws + OFF_BSUMS);
    ushort*       WT     = (ushort*)(ws + OFF_WT);
    unsigned int* ev     = (unsigned int*)(ws + OFF_EV);

    (void)hipMemsetAsync(ws, 0, 200256, stream);   // flag + counts

    k_wprep<<<256, 256, 0, stream>>>(W, WT, flag);
    k_hist<<<(N_EDGES + 255) / 256, 256, 0, stream>>>(ROWS, counts);
    k_scan1<<<196, 256, 0, stream>>>(counts, rptr, bsums, N_NODES);
    k_scan2<<<1, 256, 0, stream>>>(bsums, 196);
    k_scan3<<<196, 256, 0, stream>>>(rptr, cursor, counts, bsums, N_NODES);
    k_scatter<<<(N_EDGES + 255) / 256, 256, 0, stream>>>(ROWS, COLS, VALS, cursor, ev, flag);
    k_spmm<<<N_NODES / 4, 256, 0, stream>>>(X, ev, rptr, counts, flag, d_out);
    k_gemm<<<(N_NODES + 63) / 64, 256, 0, stream>>>(d_out, WT, flag);
}